// Round 16
// baseline (120.397 us; speedup 1.0000x reference)
//
#include <hip/hip_runtime.h>

// Problem constants (match reference): B=64, L=2048, H=256, K=32
#define LL 2048
#define BB 64
#define HH 256
#define KK 32

#define NB  256    // 1 block/CU (LDS ~145 KB/block), 16 waves/CU resident
#define WPB 16     // waves per block (1024 threads)

typedef __attribute__((ext_vector_type(8))) short  short8;   // 8 bf16 (4 VGPRs)
typedef __attribute__((ext_vector_type(4))) float  f32x4;

__device__ __forceinline__ float softplus_f(float x) {
    return x > 20.f ? x : __logf(1.f + __expf(x));
}
// round-to-nearest-even fp32 -> bf16
__device__ __forceinline__ unsigned f2bf(float x) {
    unsigned u = __builtin_bit_cast(unsigned, x);
    return (u + 0x7FFFu + ((u >> 16) & 1u)) >> 16;
}

struct RowT { float4 h, c, t, o, d; };

__device__ __forceinline__ RowT load_row(
    const float* __restrict__ hidden, const float* __restrict__ cell,
    const float* __restrict__ ctarg,  const float* __restrict__ outp,
    const float* __restrict__ decay,  int r, int lane)
{
    const int base = r * HH + lane * 4;
    RowT x;
    x.h = *(const float4*)(hidden + base);
    x.c = *(const float4*)(cell   + base);
    x.t = *(const float4*)(ctarg  + base);
    x.o = *(const float4*)(outp   + base);
    x.d = *(const float4*)(decay  + base);
    return x;
}

// Row J: compute v = o*tanh(c_sim), write v (row J) and h (row 8+J) bf16x4
// to the swizzled per-wave A-tile. (Verbatim from the 68.4 us champion.)
template<int J>
__device__ __forceinline__ void STrow(char* Aw, const RowT& R, float stv, int lane)
{
    float4 v;
    float cs, e2;
    cs = R.t.x + (R.c.x - R.t.x) * __expf(-R.d.x * stv); e2 = __expf(2.f * cs); v.x = R.o.x * ((e2 - 1.f) / (e2 + 1.f));
    cs = R.t.y + (R.c.y - R.t.y) * __expf(-R.d.y * stv); e2 = __expf(2.f * cs); v.y = R.o.y * ((e2 - 1.f) / (e2 + 1.f));
    cs = R.t.z + (R.c.z - R.t.z) * __expf(-R.d.z * stv); e2 = __expf(2.f * cs); v.z = R.o.z * ((e2 - 1.f) / (e2 + 1.f));
    cs = R.t.w + (R.c.w - R.t.w) * __expf(-R.d.w * stv); e2 = __expf(2.f * cs); v.w = R.o.w * ((e2 - 1.f) / (e2 + 1.f));
    const int swz = (J & 7) << 4;      // (8+J)&7 == J&7
    *(uint2*)(Aw + ((J * 512 + lane * 8) ^ swz)) =
        make_uint2(f2bf(v.x) | (f2bf(v.y) << 16), f2bf(v.z) | (f2bf(v.w) << 16));
    *(uint2*)(Aw + (((8 + J) * 512 + lane * 8) ^ swz)) =
        make_uint2(f2bf(R.h.x) | (f2bf(R.h.y) << 16), f2bf(R.h.z) | (f2bf(R.h.w) << 16));
}

// R9 (68.4 us) per-wave pipeline, unchanged. Only the block geometry moved:
// 16 waves/block, 1 block/CU -> 16 resident waves/CU (was 12).
__global__ __launch_bounds__(1024, 4) void nhll_main(
    const int*   __restrict__ events,   // [B, L]
    const int*   __restrict__ lens,     // [B]
    const float* __restrict__ ttime,    // [B]
    const float* __restrict__ hidden,   // [L, B, H]
    const float* __restrict__ cell,     // [L, B, H]
    const float* __restrict__ ctarg,    // [L, B, H]
    const float* __restrict__ outp,     // [L, B, H]
    const float* __restrict__ decay,    // [L, B, H]
    const float* __restrict__ simt,     // [L, B]
    const float* __restrict__ W,        // [H, K]
    const float* __restrict__ bias,     // [K]
    float*       __restrict__ partial)  // [NB]
{
    __shared__ __align__(16) char  WTs[KK * HH * 2];        // 16 KB W^T bf16, swizzled
    __shared__ __align__(16) char  Als[WPB][16 * HH * 2];   // 8 KB per wave (128 KB)
    __shared__ int   pfx[BB + 1];
    __shared__ float coef_s[BB];
    __shared__ float bias_s[KK];
    __shared__ float wacc[WPB];

    const int tid  = threadIdx.x;
    const int lane = tid & 63;
    const int q    = tid >> 6;      // wave id 0..15
    const int g    = lane >> 4;     // h-octet within K-chunk
    const int m    = lane & 15;     // A-row / C-col index

    // ---- one-time: W^T bf16 into LDS (row k, position h=tid, swizzled) ----
    if (tid < HH) {
        const float* wrow = &W[tid * KK];
#pragma unroll
        for (int k = 0; k < KK; ++k) {
            const int byte = (k * 512 + tid * 2) ^ ((k & 7) << 4);
            *(unsigned short*)(WTs + byte) = (unsigned short)f2bf(wrow[k]);
        }
    }
    if (tid < KK) bias_s[tid] = bias[tid];
    if (tid < BB) {                 // wave 0: scan lens -> prefix sums
        const int ln = lens[tid];
        coef_s[tid] = ttime[tid] / (float)ln;
        int s = ln;
#pragma unroll
        for (int mm = 1; mm < 64; mm <<= 1) {
            const int t = __shfl_up(s, mm, 64);
            if (lane >= mm) s += t;
        }
        pfx[tid + 1] = s;
        if (tid == 0) pfx[0] = 0;
    }
    __syncthreads();

    const float b_lo = bias_s[m];
    const float b_hi = bias_s[16 + m];
    const int   T      = pfx[BB];
    const int   ntiles = (T + 7) >> 3;
    char* Aw = Als[q];
    float acc = 0.f;

    for (int tile = blockIdx.x * WPB + q; tile < ntiles; tile += NB * WPB) {
        // ---- parallel metadata: lane j (j = lane&7) owns flat row tile*8+j ----
        int i = tile * 8 + (lane & 7);
        const int valid = (i < T) ? 1 : 0;
        if (!valid) i = T - 1;                    // clamp; masked below
        int lo = 0, hi = BB;
#pragma unroll
        for (int s = 0; s < 6; ++s) {
            const int mid = (lo + hi) >> 1;
            if (pfx[mid] <= i) lo = mid; else hi = mid;
        }
        const int   b    = lo;
        const int   l    = i - pfx[b];
        const int   r    = l * BB + b;
        const float st   = simt[r];
        const float coef = valid ? coef_s[b] : 0.f;
        const int   e    = events[b * LL + l + 1];   // l+1 <= len <= 2046

        int rs[8]; float ss[8];
#pragma unroll
        for (int j = 0; j < 8; ++j) {
            rs[j] = __shfl(r, j, 64);
            ss[j] = __shfl(st, j, 64);
        }

        // ---- staging with 3-deep load rotation ----
        RowT b0 = load_row(hidden, cell, ctarg, outp, decay, rs[0], lane);
        RowT b1 = load_row(hidden, cell, ctarg, outp, decay, rs[1], lane);
        RowT b2 = load_row(hidden, cell, ctarg, outp, decay, rs[2], lane);
        STrow<0>(Aw, b0, ss[0], lane); b0 = load_row(hidden, cell, ctarg, outp, decay, rs[3], lane);
        STrow<1>(Aw, b1, ss[1], lane); b1 = load_row(hidden, cell, ctarg, outp, decay, rs[4], lane);
        STrow<2>(Aw, b2, ss[2], lane); b2 = load_row(hidden, cell, ctarg, outp, decay, rs[5], lane);
        STrow<3>(Aw, b0, ss[3], lane); b0 = load_row(hidden, cell, ctarg, outp, decay, rs[6], lane);
        STrow<4>(Aw, b1, ss[4], lane); b1 = load_row(hidden, cell, ctarg, outp, decay, rs[7], lane);
        STrow<5>(Aw, b2, ss[5], lane);
        STrow<6>(Aw, b0, ss[6], lane);
        STrow<7>(Aw, b1, ss[7], lane);

        // ---- MFMA: C[16][32], A and both W-tiles from LDS ----
        f32x4 C0 = {0.f,0.f,0.f,0.f}, C1 = {0.f,0.f,0.f,0.f};
        const int abase = m * 512 + 16 * g;
        const int swz   = (m & 7) << 4;
#pragma unroll
        for (int c = 0; c < 8; ++c) {
            const short8 a  = *(const short8*)(Aw  + ((abase + 64 * c) ^ swz));
            const short8 w0 = *(const short8*)(WTs + ((abase + 64 * c) ^ swz));
            const short8 w1 = *(const short8*)(WTs + ((abase + 8192 + 64 * c) ^ swz));
            C0 = __builtin_amdgcn_mfma_f32_16x16x32_bf16(a, w0, C0, 0, 0, 0);
            C1 = __builtin_amdgcn_mfma_f32_16x16x32_bf16(a, w1, C1, 0, 0, 0);
        }

        // ---- term 2: C rows 0-7 (g<2), row = 4g+reg, col = m ----
        float sp[4];
#pragma unroll
        for (int reg = 0; reg < 4; ++reg)
            sp[reg] = softplus_f(C0[reg] + b_lo) + softplus_f(C1[reg] + b_hi);
#pragma unroll
        for (int mk = 1; mk <= 8; mk <<= 1) {
#pragma unroll
            for (int reg = 0; reg < 4; ++reg) sp[reg] += __shfl_xor(sp[reg], mk, 64);
        }
        float t2 = 0.f;
#pragma unroll
        for (int reg = 0; reg < 4; ++reg) {
            const float cf = __shfl(coef, 4 * reg + 4 * g, 64) * 0.f + __shfl(coef, 4 * g + reg, 64);
            t2 += cf * sp[reg];
        }
        if (m == 0 && g < 2) acc += t2;

        // ---- term 1: C rows 8-15 (g=2,3) gathered at column e ----
        float kv = 0.f, kb = 0.f;
#pragma unroll
        for (int rr = 0; rr < 8; ++rr) {
            const int   er   = __shfl(e, rr, 64);            // e of flat row rr
            const float cand = (er < 16) ? C0[rr & 3] : C1[rr & 3];
            const float val  = __shfl(cand, 32 + ((rr >> 2) << 4) + (er & 15), 64);
            const float be   = bias_s[er];
            if (lane == rr) { kv = val; kb = be; }
        }
        if (lane < 8 && valid)
            acc -= __logf(softplus_f(kv + kb));
    }

    // wave reduce + block reduce
#pragma unroll
    for (int mk = 1; mk < 64; mk <<= 1) acc += __shfl_xor(acc, mk, 64);
    if (lane == 0) wacc[q] = acc;
    __syncthreads();
    if (tid == 0) {
        float s = 0.f;
#pragma unroll
        for (int w = 0; w < WPB; ++w) s += wacc[w];
        partial[blockIdx.x] = s;
    }
}

// Output: single float32 scalar.
__global__ __launch_bounds__(256) void nhll_finalize(
    const float* __restrict__ partial, float* __restrict__ out)
{
    __shared__ float red[4];
    float s = 0.f;
    for (int i = threadIdx.x; i < NB; i += 256) s += partial[i];
    for (int mk = 1; mk < 64; mk <<= 1) s += __shfl_xor(s, mk, 64);
    if ((threadIdx.x & 63) == 0) red[threadIdx.x >> 6] = s;
    __syncthreads();
    if (threadIdx.x == 0)
        out[0] = red[0] + red[1] + red[2] + red[3];
}

extern "C" void kernel_launch(void* const* d_in, const int* in_sizes, int n_in,
                              void* d_out, int out_size, void* d_ws, size_t ws_size,
                              hipStream_t stream) {
    const int*   events = (const int*)  d_in[0];   // event_seqs  [B,L] int32
    const int*   lens   = (const int*)  d_in[1];   // seqs_length [B]   int32
    const float* ttime  = (const float*)d_in[2];   // total_time  [B]
    const float* hidden = (const float*)d_in[3];   // [L,B,H]
    const float* cell   = (const float*)d_in[4];   // [L,B,H]
    const float* ctarg  = (const float*)d_in[5];   // [L,B,H]
    const float* outp   = (const float*)d_in[6];   // [L,B,H]
    const float* decay  = (const float*)d_in[7];   // [L,B,H]
    const float* simt   = (const float*)d_in[8];   // [L,B]
    const float* W      = (const float*)d_in[9];   // [H,K]
    const float* bias   = (const float*)d_in[10];  // [K]

    float* part = (float*)d_ws;                    // NB floats
    float* out  = (float*)d_out;

    nhll_main<<<NB, 1024, 0, stream>>>(events, lens, ttime, hidden, cell, ctarg,
                                       outp, decay, simt, W, bias, part);
    nhll_finalize<<<1, 256, 0, stream>>>(part, out);
}

// Round 17
// 77.471 us; speedup vs baseline: 1.5541x; 1.5541x over previous
//
#include <hip/hip_runtime.h>

// Problem constants (match reference): B=64, L=2048, H=256, K=32
#define LL 2048
#define BB 64
#define HH 256
#define KK 32

#define NB  768    // 3 blocks/CU (LDS-limited: ~49.5 KB/block)
#define WPB 4      // waves per block

typedef __attribute__((ext_vector_type(8))) short  short8;   // 8 bf16 (4 VGPRs)
typedef __attribute__((ext_vector_type(4))) float  f32x4;

__device__ __forceinline__ float softplus_f(float x) {
    return x > 20.f ? x : __logf(1.f + __expf(x));
}
// round-to-nearest-even fp32 -> bf16
__device__ __forceinline__ unsigned f2bf(float x) {
    unsigned u = __builtin_bit_cast(unsigned, x);
    return (u + 0x7FFFu + ((u >> 16) & 1u)) >> 16;
}

struct RowT { float4 h, c, t, o, d; };

__device__ __forceinline__ RowT load_row(
    const float* __restrict__ hidden, const float* __restrict__ cell,
    const float* __restrict__ ctarg,  const float* __restrict__ outp,
    const float* __restrict__ decay,  int r, int lane)
{
    const int base = r * HH + lane * 4;
    RowT x;
    x.h = *(const float4*)(hidden + base);
    x.c = *(const float4*)(cell   + base);
    x.t = *(const float4*)(ctarg  + base);
    x.o = *(const float4*)(outp   + base);
    x.d = *(const float4*)(decay  + base);
    return x;
}

// Row J: compute v = o*tanh(c_sim), write v (row J) and h (row 8+J) bf16x4
// to the swizzled per-wave A-tile. (Verbatim from the 68.4 us champion.)
template<int J>
__device__ __forceinline__ void STrow(char* Aw, const RowT& R, float stv, int lane)
{
    float4 v;
    float cs, e2;
    cs = R.t.x + (R.c.x - R.t.x) * __expf(-R.d.x * stv); e2 = __expf(2.f * cs); v.x = R.o.x * ((e2 - 1.f) / (e2 + 1.f));
    cs = R.t.y + (R.c.y - R.t.y) * __expf(-R.d.y * stv); e2 = __expf(2.f * cs); v.y = R.o.y * ((e2 - 1.f) / (e2 + 1.f));
    cs = R.t.z + (R.c.z - R.t.z) * __expf(-R.d.z * stv); e2 = __expf(2.f * cs); v.z = R.o.z * ((e2 - 1.f) / (e2 + 1.f));
    cs = R.t.w + (R.c.w - R.t.w) * __expf(-R.d.w * stv); e2 = __expf(2.f * cs); v.w = R.o.w * ((e2 - 1.f) / (e2 + 1.f));
    const int swz = (J & 7) << 4;      // (8+J)&7 == J&7
    *(uint2*)(Aw + ((J * 512 + lane * 8) ^ swz)) =
        make_uint2(f2bf(v.x) | (f2bf(v.y) << 16), f2bf(v.z) | (f2bf(v.w) << 16));
    *(uint2*)(Aw + (((8 + J) * 512 + lane * 8) ^ swz)) =
        make_uint2(f2bf(R.h.x) | (f2bf(R.h.y) << 16), f2bf(R.h.z) | (f2bf(R.h.w) << 16));
}

// ---- prep A (1 block, 64 threads): pfx, coef, T into workspace ----
__global__ __launch_bounds__(64) void nhll_prepA(
    const int*   __restrict__ lens,     // [B]
    const float* __restrict__ ttime,    // [B]
    int*   __restrict__ Tout,           // [1]
    float* __restrict__ coef_w,         // [B]
    int*   __restrict__ pfx_w)          // [B+1]
{
    const int tid = threadIdx.x;        // 0..63 == one wave
    const int ln  = lens[tid];
    coef_w[tid] = ttime[tid] / (float)ln;
    int s = ln;
#pragma unroll
    for (int mm = 1; mm < 64; mm <<= 1) {
        const int t = __shfl_up(s, mm, 64);
        if (tid >= mm) s += t;
    }
    pfx_w[tid + 1] = s;
    if (tid == 0)  pfx_w[0] = 0;
    if (tid == 63) Tout[0] = s;
}

// ---- prep B: per flat row i, mtab[i] = { r | e<<17 | b<<22 , bits(st) } ----
__global__ __launch_bounds__(256) void nhll_prepB(
    const int*   __restrict__ events,   // [B, L]
    const float* __restrict__ simt,     // [L, B]
    const int*   __restrict__ Tin,      // [1]
    const int*   __restrict__ pfx_w,    // [B+1]
    uint2*       __restrict__ mtab)
{
    __shared__ int pfx[BB + 1];
    if (threadIdx.x < BB + 1) pfx[threadIdx.x] = pfx_w[threadIdx.x];
    __syncthreads();
    const int T = Tin[0];
    for (int i = blockIdx.x * 256 + threadIdx.x; i < T; i += gridDim.x * 256) {
        int lo = 0, hi = BB;
#pragma unroll
        for (int s = 0; s < 6; ++s) {
            const int mid = (lo + hi) >> 1;
            if (pfx[mid] <= i) lo = mid; else hi = mid;
        }
        const int b = lo;
        const int l = i - pfx[b];
        const int r = l * BB + b;
        const int e = events[b * LL + l + 1];        // l+1 <= len <= 2046
        mtab[i] = make_uint2((unsigned)r | ((unsigned)e << 17) | ((unsigned)b << 22),
                             __builtin_bit_cast(unsigned, simt[r]));
    }
}

// ---- main: R9 (68.4 us) pipeline; metadata from precomputed mtab ----
__global__ __launch_bounds__(256, 3) void nhll_main(
    const float* __restrict__ hidden,   // [L, B, H]
    const float* __restrict__ cell,     // [L, B, H]
    const float* __restrict__ ctarg,    // [L, B, H]
    const float* __restrict__ outp,     // [L, B, H]
    const float* __restrict__ decay,    // [L, B, H]
    const float* __restrict__ W,        // [H, K]
    const float* __restrict__ bias,     // [K]
    const int*   __restrict__ Tin,      // [1]
    const float* __restrict__ coef_w,   // [B]
    const uint2* __restrict__ mtab,     // [T]
    float*       __restrict__ partial)  // [NB]
{
    __shared__ __align__(16) char  WTs[KK * HH * 2];        // 16 KB W^T bf16, swizzled
    __shared__ __align__(16) char  Als[WPB][16 * HH * 2];   // 8 KB per wave
    __shared__ float coef_s[BB];
    __shared__ float bias_s[KK];
    __shared__ float wacc[WPB];

    const int tid  = threadIdx.x;
    const int lane = tid & 63;
    const int q    = tid >> 6;
    const int g    = lane >> 4;     // h-octet within K-chunk
    const int m    = lane & 15;     // A-row / C-col index

    // ---- one-time: W^T bf16 into LDS (row k, position h=tid, swizzled) ----
    {
        const float* wrow = &W[tid * KK];
#pragma unroll
        for (int k = 0; k < KK; ++k) {
            const int byte = (k * 512 + tid * 2) ^ ((k & 7) << 4);
            *(unsigned short*)(WTs + byte) = (unsigned short)f2bf(wrow[k]);
        }
    }
    if (tid < KK) bias_s[tid] = bias[tid];
    if (tid < BB) coef_s[tid] = coef_w[tid];
    __syncthreads();

    const float b_lo = bias_s[m];
    const float b_hi = bias_s[16 + m];
    const int   T      = Tin[0];
    const int   ntiles = (T + 7) >> 3;
    char* Aw = Als[q];
    float acc = 0.f;

    for (int tile = blockIdx.x * WPB + q; tile < ntiles; tile += NB * WPB) {
        // ---- metadata: one coalesced 8B load per lane (lane j owns row tile*8+j) ----
        int i = tile * 8 + (lane & 7);
        const int valid = (i < T) ? 1 : 0;
        if (!valid) i = T - 1;                    // clamp; masked below
        const uint2 md   = mtab[i];
        const int   r    = md.x & 0x1FFFF;
        const int   e    = (md.x >> 17) & 31;
        const int   bb   = md.x >> 22;
        const float st   = __builtin_bit_cast(float, md.y);
        const float coef = valid ? coef_s[bb] : 0.f;

        int rs[8]; float ss[8];
#pragma unroll
        for (int j = 0; j < 8; ++j) {
            rs[j] = __shfl(r, j, 64);
            ss[j] = __shfl(st, j, 64);
        }

        // ---- staging with 3-deep load rotation ----
        RowT b0 = load_row(hidden, cell, ctarg, outp, decay, rs[0], lane);
        RowT b1 = load_row(hidden, cell, ctarg, outp, decay, rs[1], lane);
        RowT b2 = load_row(hidden, cell, ctarg, outp, decay, rs[2], lane);
        STrow<0>(Aw, b0, ss[0], lane); b0 = load_row(hidden, cell, ctarg, outp, decay, rs[3], lane);
        STrow<1>(Aw, b1, ss[1], lane); b1 = load_row(hidden, cell, ctarg, outp, decay, rs[4], lane);
        STrow<2>(Aw, b2, ss[2], lane); b2 = load_row(hidden, cell, ctarg, outp, decay, rs[5], lane);
        STrow<3>(Aw, b0, ss[3], lane); b0 = load_row(hidden, cell, ctarg, outp, decay, rs[6], lane);
        STrow<4>(Aw, b1, ss[4], lane); b1 = load_row(hidden, cell, ctarg, outp, decay, rs[7], lane);
        STrow<5>(Aw, b2, ss[5], lane);
        STrow<6>(Aw, b0, ss[6], lane);
        STrow<7>(Aw, b1, ss[7], lane);

        // ---- MFMA: C[16][32], A and both W-tiles from LDS ----
        f32x4 C0 = {0.f,0.f,0.f,0.f}, C1 = {0.f,0.f,0.f,0.f};
        const int abase = m * 512 + 16 * g;
        const int swz   = (m & 7) << 4;
#pragma unroll
        for (int c = 0; c < 8; ++c) {
            const short8 a  = *(const short8*)(Aw  + ((abase + 64 * c) ^ swz));
            const short8 w0 = *(const short8*)(WTs + ((abase + 64 * c) ^ swz));
            const short8 w1 = *(const short8*)(WTs + ((abase + 8192 + 64 * c) ^ swz));
            C0 = __builtin_amdgcn_mfma_f32_16x16x32_bf16(a, w0, C0, 0, 0, 0);
            C1 = __builtin_amdgcn_mfma_f32_16x16x32_bf16(a, w1, C1, 0, 0, 0);
        }

        // ---- term 2: C rows 0-7 (g<2), row = 4g+reg, col = m ----
        float sp[4];
#pragma unroll
        for (int reg = 0; reg < 4; ++reg)
            sp[reg] = softplus_f(C0[reg] + b_lo) + softplus_f(C1[reg] + b_hi);
#pragma unroll
        for (int mk = 1; mk <= 8; mk <<= 1) {
#pragma unroll
            for (int reg = 0; reg < 4; ++reg) sp[reg] += __shfl_xor(sp[reg], mk, 64);
        }
        float t2 = 0.f;
#pragma unroll
        for (int reg = 0; reg < 4; ++reg) {
            const float cf = __shfl(coef, 4 * g + reg, 64);  // coef of flat row 4g+reg
            t2 += cf * sp[reg];
        }
        if (m == 0 && g < 2) acc += t2;

        // ---- term 1: C rows 8-15 (g=2,3) gathered at column e ----
        float kv = 0.f, kb = 0.f;
#pragma unroll
        for (int rr = 0; rr < 8; ++rr) {
            const int   er   = __shfl(e, rr, 64);            // e of flat row rr
            const float cand = (er < 16) ? C0[rr & 3] : C1[rr & 3];
            const float val  = __shfl(cand, 32 + ((rr >> 2) << 4) + (er & 15), 64);
            const float be   = bias_s[er];
            if (lane == rr) { kv = val; kb = be; }
        }
        if (lane < 8 && valid)
            acc -= __logf(softplus_f(kv + kb));
    }

    // wave reduce + block reduce
#pragma unroll
    for (int mk = 1; mk < 64; mk <<= 1) acc += __shfl_xor(acc, mk, 64);
    if (lane == 0) wacc[q] = acc;
    __syncthreads();
    if (tid == 0) partial[blockIdx.x] = wacc[0] + wacc[1] + wacc[2] + wacc[3];
}

// Output: single float32 scalar.
__global__ __launch_bounds__(256) void nhll_finalize(
    const float* __restrict__ partial, float* __restrict__ out)
{
    __shared__ float red[4];
    float s = 0.f;
    for (int i = threadIdx.x; i < NB; i += 256) s += partial[i];
    for (int mk = 1; mk < 64; mk <<= 1) s += __shfl_xor(s, mk, 64);
    if ((threadIdx.x & 63) == 0) red[threadIdx.x >> 6] = s;
    __syncthreads();
    if (threadIdx.x == 0)
        out[0] = red[0] + red[1] + red[2] + red[3];
}

extern "C" void kernel_launch(void* const* d_in, const int* in_sizes, int n_in,
                              void* d_out, int out_size, void* d_ws, size_t ws_size,
                              hipStream_t stream) {
    const int*   events = (const int*)  d_in[0];   // event_seqs  [B,L] int32
    const int*   lens   = (const int*)  d_in[1];   // seqs_length [B]   int32
    const float* ttime  = (const float*)d_in[2];   // total_time  [B]
    const float* hidden = (const float*)d_in[3];   // [L,B,H]
    const float* cell   = (const float*)d_in[4];   // [L,B,H]
    const float* ctarg  = (const float*)d_in[5];   // [L,B,H]
    const float* outp   = (const float*)d_in[6];   // [L,B,H]
    const float* decay  = (const float*)d_in[7];   // [L,B,H]
    const float* simt   = (const float*)d_in[8];   // [L,B]
    const float* W      = (const float*)d_in[9];   // [H,K]
    const float* bias   = (const float*)d_in[10];  // [K]

    // workspace layout (bytes):
    //   0     : int T
    //   64    : coef[64]  (256 B)
    //   320   : pfx[65]   (260 B)
    //   1024  : partial[NB] (3 KB)
    //   4096  : mtab[<=130944] uint2 (~1.05 MB)
    char*  ws     = (char*)d_ws;
    int*   Tslot  = (int*)  (ws + 0);
    float* coef_w = (float*)(ws + 64);
    int*   pfx_w  = (int*)  (ws + 320);
    float* part   = (float*)(ws + 1024);
    uint2* mtab   = (uint2*)(ws + 4096);
    float* out    = (float*)d_out;

    nhll_prepA<<<1, 64, 0, stream>>>(lens, ttime, Tslot, coef_w, pfx_w);
    nhll_prepB<<<128, 256, 0, stream>>>(events, simt, Tslot, pfx_w, mtab);
    nhll_main<<<NB, 256, 0, stream>>>(hidden, cell, ctarg, outp, decay, W, bias,
                                      Tslot, coef_w, mtab, part);
    nhll_finalize<<<1, 256, 0, stream>>>(part, out);
}